// Round 10
// baseline (211.069 us; speedup 1.0000x reference)
//
#include <hip/hip_runtime.h>
#include <cstdint>

#define NPRED 25200      // total predictions (8400 positions * 3 anchors)
#define NPOS  8400
#define NCLS  80
#define CAP   512        // max boxes per class (mean ~315, sigma ~18)
#define MW    8          // u64 mask words per row (512/64)
#define NCHUNK 132       // 64-position chunks: 100 (s0) + 25 (s1) + 7 (s2 tail)

__device__ __forceinline__ float sigmoidf_(float x) { return 1.0f / (1.0f + expf(-x)); }

// Block = (64-position chunk, anchor), 64 threads. REGISTER-RESIDENT class
// logits (v[80] in VGPRs; (64,2) bounds -> 256 VGPR cap, no spill).
// Op order exact: fmax ascending, serial sum ascending, strict-> argmax
// ascending; best = beste/s*obj is the ref expression at the argmax.
__global__ __launch_bounds__(64, 2) void decode_kernel(
    const float* __restrict__ ps, const float* __restrict__ pm, const float* __restrict__ pl,
    float* __restrict__ out,
    float4* __restrict__ g_boxin, uint64_t* __restrict__ g_key)
{
    int chunk = blockIdx.x;
    int a     = blockIdx.y;
    int t     = threadIdx.x;

    const float* p; int HW, W, base, si; float stride; int w0;
    if (chunk < 100)      { p = ps; HW = 6400; W = 80; stride = 8.f;  base = 0;    si = 0; w0 = chunk * 64; }
    else if (chunk < 125) { p = pm; HW = 1600; W = 40; stride = 16.f; base = 6400; si = 1; w0 = (chunk - 100) * 64; }
    else                  { p = pl; HW = 400;  W = 20; stride = 32.f; base = 8000; si = 2; w0 = (chunk - 125) * 64; }

    int local = w0 + t;
    bool valid = local < HW;
    int lclamp = valid ? local : (HW - 1);

    const float* cbase = p + (size_t)(3 + a * NCLS) * HW + lclamp;
    float v[NCLS];
#pragma unroll
    for (int c = 0; c < NCLS; c++) v[c] = cbase[(size_t)c * HW];

    float objl = p[(size_t)a * HW + lclamp];
    const float* rb = p + (size_t)(3 + 3 * NCLS + a * 4) * HW + lclamp;
    float tx = rb[0], ty = rb[(size_t)HW], tw = rb[(size_t)2 * HW], th = rb[(size_t)3 * HW];

    // pass A: max (ascending, order-exact)
    float m = -INFINITY;
#pragma unroll
    for (int c = 0; c < NCLS; c++) m = fmaxf(m, v[c]);
    // pass B: serial ascending sum + argmax of e (strict >, ascending)
    float s = 0.f; float beste = -1.f; int bi = 0;
#pragma unroll
    for (int c = 0; c < NCLS; c++) {
        float e = expf(v[c] - m);
        s += e;
        if (e > beste) { beste = e; bi = c; }
    }
    float obj = sigmoidf_(objl);
    float best = beste / s * obj;             // == ref's (e/s)*obj at argmax

    if (!valid) return;

    const float AW[9] = {10.f,16.f,33.f, 30.f,62.f,59.f, 116.f,156.f,373.f};
    const float AH[9] = {13.f,30.f,23.f, 61.f,45.f,119.f, 90.f,198.f,326.f};
    float aw = AW[si*3 + a], ah = AH[si*3 + a];

    int y = local / W;
    int x = local - y * W;
    float cx = (sigmoidf_(tx) + (float)x) * stride;
    float cy = (sigmoidf_(ty) + (float)y) * stride;
    float bw = expf(tw) * aw;
    float bh = expf(th) * ah;
    float x1 = fminf(fmaxf((cx - bw / 2.f) / 640.f, 0.f), 1.f);
    float y1 = fminf(fmaxf((cy - bh / 2.f) / 640.f, 0.f), 1.f);
    float x2 = fminf(fmaxf((cx + bw / 2.f) / 640.f, 0.f), 1.f);
    float y2 = fminf(fmaxf((cy + bh / 2.f) / 640.f, 0.f), 1.f);

    int g = (base + local) * 3 + a;           // reference global ordering
    float clsf = (float)bi;
    float* o = out + (size_t)g * 7;
    o[0] = x1; o[1] = y1; o[2] = x2; o[3] = y2;
    o[4] = best; o[5] = clsf; o[6] = 0.f;

    if (best >= 0.001f) {
        float off2 = clsf * 2.0f;             // ref IoU uses class-offset boxes
        g_boxin[g] = make_float4(x1 + off2, y1 + off2, x2 + off2, y2 + off2);
        unsigned u = __float_as_uint(best);
        u = (u & 0x80000000u) ? ~u : (u | 0x80000000u);
        g_key[g] = ((uint64_t)bi << 47) | ((uint64_t)(~u) << 15) | (uint64_t)g;
    } else {
        g_key[g] = (uint64_t)127 << 47;       // sentinel class: never matched
    }
}

// wave-level bucket step: ballot-compact 2 keys/thread; lane0-atomic valid
// because active lanes are always a tid-prefix within the wave.
#define BUCKET2(kv)                                                       \
    {                                                                     \
        bool m0 = (int)((kv).x >> 47) == c;                               \
        bool m1 = (int)((kv).y >> 47) == c;                               \
        unsigned long long b0 = __ballot(m0);                             \
        unsigned long long b1 = __ballot(m1);                             \
        int total = __popcll(b0) + __popcll(b1);                          \
        int bs = 0;                                                       \
        if (lane == 0 && total) bs = atomicAdd(&ln_s, total);             \
        bs = __shfl(bs, 0);                                               \
        unsigned long long lower = ((unsigned long long)1 << lane) - 1;   \
        int off0 = bs + __popcll(b0 & lower);                             \
        int off1 = bs + __popcll(b0) + __popcll(b1 & lower);              \
        if (m0 && off0 < CAP) key_s[off0] = (kv).x;                       \
        if (m1 && off1 < CAP) key_s[off1] = (kv).y;                       \
    }

// ONE block per class, 1024 threads. BYTE-IDENTICAL to R9's fused kernel.
// This round is a measurement round: kernel_launch launches this 4x (it is
// idempotent -- reads only decode's outputs, writes the same keep-flag set
// every run). Total time = base + 3x(fused+gap) pins the fused duration,
// which top-5 truncation has hidden for 3 rounds.
__global__ __launch_bounds__(1024, 4) void nms_fused_kernel(
    const uint64_t* __restrict__ g_key, const float4* __restrict__ g_boxin,
    float* __restrict__ out)
{
    int c = blockIdx.x;
    int tid = threadIdx.x;

    __shared__ alignas(16) uint64_t key_s[CAP];   // 4 KB (class-c keys)
    __shared__ float4   boxu_s[CAP];              // 8 KB (matching offset boxes)
    __shared__ float4   sbox_s[CAP + 64];         // 9 KB (sorted, +64 sentinel)
    __shared__ int      sg_s[CAP];                // 2 KB (sorted -> pred idx)
    __shared__ uint64_t mask_s[MW * CAP];         // 32 KB (suppression bitmask)
    __shared__ int      ln_s;

    if (tid == 0) ln_s = 0;
    __syncthreads();

    // ---- phase 0: bucket class-c keys; 6 full strip-2 rounds + prefix tail
    {
        int lane = tid & 63;
        const ulonglong2* kp = (const ulonglong2*)g_key;
        const int HALF = NPRED / 2;          // 12600
        const int R2 = HALF >> 11;           // 6 full 2048-item rounds
        for (int r = 0; r < R2; r++) {
            int i0 = (r << 11) + tid;        // in-bounds for ALL threads
            ulonglong2 ka = kp[i0];
            ulonglong2 kb = kp[i0 + 1024];   // both loads in flight
            BUCKET2(ka);
            BUCKET2(kb);
        }
        int ti = (R2 << 11) + tid;           // 12288 + tid (prefix-active)
        if (ti < HALF) {
            ulonglong2 ka = kp[ti];
            BUCKET2(ka);
        }
    }
    __syncthreads();
    int n = ln_s; if (n > CAP) n = CAP;
    if (n == 0) return;                       // uniform (all read ln_s)
    int nw = (n + 63) >> 6;

    // ---- phase 0b: gather boxes by g; sentinel-fill pad for the IoU loop
    for (int i = tid; i < n; i += 1024)
        boxu_s[i] = g_boxin[key_s[i] & 0x7FFF];
    for (int i = n + tid; i < n + 64; i += 1024)
        sbox_s[i] = make_float4(3e30f, 3e30f, 3e30f, 3e30f);
    __syncthreads();

    // ---- rank-by-count sort (keys unique: low 15 bits = global pred idx).
    for (int i0 = 0; i0 < n; i0 += 256) {
        int item = i0 + (tid >> 2);
        int sub  = tid & 3;
        bool act = item < n;
        int r = 0;
        uint64_t k = 0;
        if (act) {
            k = key_s[item];
            int nq = (((n + 3) >> 2) + 1) & ~1;    // even, >= ceil(n/4)
            int lo = sub * nq; if (lo > n) lo = n; // lo even (or == n)
            int hi = lo + nq;  if (hi > n) hi = n;
            int jj = lo;
            for (; jj + 8 <= hi; jj += 8) {        // 4x ds_read_b128 in flight
                ulonglong2 p0 = *(const ulonglong2*)&key_s[jj];
                ulonglong2 p1 = *(const ulonglong2*)&key_s[jj + 2];
                ulonglong2 p2 = *(const ulonglong2*)&key_s[jj + 4];
                ulonglong2 p3 = *(const ulonglong2*)&key_s[jj + 6];
                r += (p0.x < k) + (p0.y < k) + (p1.x < k) + (p1.y < k)
                   + (p2.x < k) + (p2.y < k) + (p3.x < k) + (p3.y < k);
            }
            for (; jj + 2 <= hi; jj += 2) {
                ulonglong2 p0 = *(const ulonglong2*)&key_s[jj];
                r += (p0.x < k) + (p0.y < k);
            }
            if (jj < hi) r += (key_s[jj] < k);
        }
        r += __shfl_xor(r, 1);                // quad reduce (4 lanes/item)
        r += __shfl_xor(r, 2);
        if (act && sub == 0) {
            sbox_s[r] = boxu_s[item];
            sg_s[r]   = (int)(k & 0x7FFF);
        }
    }
    __syncthreads();

    // ---- mask build: upper-triangle words only, tiled as wave-tasks.
    {
        int wid   = tid >> 6;                 // 0..15
        int lane2 = tid & 63;
        int T = nw * (nw + 1) / 2;
        for (int t = wid; t < T; t += 16) {
            int w = 0, acc = 0;               // triangular decode (wave-uniform)
            while (t >= acc + w + 1) { acc += w + 1; w++; }
            int ib = t - acc;                 // 0..w
            int i  = (ib << 6) + lane2;       // <= n+62 (covered by pad)
            float4 b4 = sbox_s[i];
            float Ai = (b4.z - b4.x) * (b4.w - b4.y);
            int j0 = w << 6;
            float4 bjc = sbox_s[j0];
            uint64_t bits = 0;
#pragma unroll 8
            for (int jq = 0; jq < 64; jq++) {
                float4 bjn = sbox_s[j0 + ((jq + 1) & 63)];  // prefetch (wrap ok)
                float xx1 = fmaxf(b4.x, bjc.x);
                float yy1 = fmaxf(b4.y, bjc.y);
                float xx2 = fminf(b4.z, bjc.z);
                float yy2 = fminf(b4.w, bjc.w);
                float ww = fmaxf(1e-28f, xx2 - xx1);
                float hh = fmaxf(1e-28f, yy2 - yy1);
                float inter = ww * hh;
                float Aj = (bjc.z - bjc.x) * (bjc.w - bjc.y);
                float iou = inter / ((Ai + Aj) - inter);   // ref op order
                if ((j0 + jq) > i && iou > 0.6f) bits |= 1ull << jq;
                bjc = bjn;
            }
            if (i < n) mask_s[w * CAP + i] = bits;
        }
    }
    __syncthreads();

    // ---- greedy bitmask scan on wave 0 (== ref's fori_loop greedy NMS)
    if (tid >= 64) return;
    int lane = tid;
    uint64_t removed = 0;                      // lane L<8 holds word L
    for (int w = 0; w < nw; w++) {
        uint64_t rw = __shfl(removed, w);
        int row = (w << 6) + lane;
        uint64_t diag = (row < n) ? mask_s[w * CAP + row] : 0ull;
        int rem = n - (w << 6);
        uint64_t valid = (rem >= 64) ? ~0ull : ((1ull << rem) - 1ull);
        uint64_t nulls = __ballot(diag == 0ull);
        uint64_t cand = ~rw & valid;
        uint64_t kw = 0;
        uint64_t it = cand & ~nulls;           // rows with in-word forward bits
        while (it) {                           // uniform serial chain (rare rows)
            int b = __ffsll((unsigned long long)it) - 1;
            kw |= 1ull << b;
            uint64_t db = __shfl(diag, b);
            it &= ~db; cand &= ~db;
            it &= ~(1ull << b);
        }
        kw |= cand & nulls;                    // surviving zero-diag rows kept

        // cooperative fold: fixed predicated 8-read unroll.
        int g  = lane >> 3;
        int wp = lane & 7;
        uint64_t acc = 0;
        if (wp >= w && wp < nw) {
            int rbase = (w << 6) + (g << 3);
#pragma unroll
            for (int bb = 0; bb < 8; bb++) {
                uint64_t mword = mask_s[wp * CAP + rbase + bb];
                if ((kw >> ((g << 3) + bb)) & 1) acc |= mword;
            }
        }
        acc |= __shfl_xor(acc, 8);
        acc |= __shfl_xor(acc, 16);
        acc |= __shfl_xor(acc, 32);
        if (lane < MW) removed |= acc;

        if (row < n && ((kw >> lane) & 1))
            out[(size_t)sg_s[row] * 7 + 6] = 1.0f;
    }
}

extern "C" void kernel_launch(void* const* d_in, const int* in_sizes, int n_in,
                              void* d_out, int out_size, void* d_ws, size_t ws_size,
                              hipStream_t stream) {
    const float* ps = (const float*)d_in[0];
    const float* pm = (const float*)d_in[1];
    const float* pl = (const float*)d_in[2];
    float* out = (float*)d_out;

    char* ws = (char*)d_ws;
    float4*   g_boxin = (float4*)ws;                       // 403,200 B (dense by g)
    uint64_t* g_key   = (uint64_t*)(ws + 409600);          // 201,600 B (dense by g)

    decode_kernel<<<dim3(NCHUNK, 3), 64, 0, stream>>>(ps, pm, pl, out, g_boxin, g_key);
    // ATTRIBUTION: fused is idempotent; 4 launches => total = base + 3x(fused+gap).
    // Resolves the fused kernel's duration (hidden below top-5 cutoff since R6).
    nms_fused_kernel<<<NCLS, 1024, 0, stream>>>(g_key, g_boxin, out);
    nms_fused_kernel<<<NCLS, 1024, 0, stream>>>(g_key, g_boxin, out);
    nms_fused_kernel<<<NCLS, 1024, 0, stream>>>(g_key, g_boxin, out);
    nms_fused_kernel<<<NCLS, 1024, 0, stream>>>(g_key, g_boxin, out);
}

// Round 12
// 121.264 us; speedup vs baseline: 1.7406x; 1.7406x over previous
//
#include <hip/hip_runtime.h>
#include <cstdint>

#define NPRED 25200      // total predictions (8400 positions * 3 anchors)
#define NPOS  8400
#define NCLS  80
#define CAP   512        // max boxes per class (mean ~315, sigma ~18)
#define MW    8          // u64 mask words per row (512/64)
#define NCHUNK 132       // 64-position chunks: 100 (s0) + 25 (s1) + 7 (s2 tail)

__device__ __forceinline__ float sigmoidf_(float x) { return 1.0f / (1.0f + expf(-x)); }

// Block = (64-position chunk, anchor), 64 threads. REGISTER-RESIDENT class
// logits (v[80] in VGPRs; (64,2) bounds -> 256 VGPR cap, no spill).
// BYTE-IDENTICAL to R9. Idempotent (no atomics; every store is a pure
// function of the inputs) -> safe to replicate for attribution.
__global__ __launch_bounds__(64, 2) void decode_kernel(
    const float* __restrict__ ps, const float* __restrict__ pm, const float* __restrict__ pl,
    float* __restrict__ out,
    float4* __restrict__ g_boxin, uint64_t* __restrict__ g_key)
{
    int chunk = blockIdx.x;
    int a     = blockIdx.y;
    int t     = threadIdx.x;

    const float* p; int HW, W, base, si; float stride; int w0;
    if (chunk < 100)      { p = ps; HW = 6400; W = 80; stride = 8.f;  base = 0;    si = 0; w0 = chunk * 64; }
    else if (chunk < 125) { p = pm; HW = 1600; W = 40; stride = 16.f; base = 6400; si = 1; w0 = (chunk - 100) * 64; }
    else                  { p = pl; HW = 400;  W = 20; stride = 32.f; base = 8000; si = 2; w0 = (chunk - 125) * 64; }

    int local = w0 + t;
    bool valid = local < HW;
    int lclamp = valid ? local : (HW - 1);

    const float* cbase = p + (size_t)(3 + a * NCLS) * HW + lclamp;
    float v[NCLS];
#pragma unroll
    for (int c = 0; c < NCLS; c++) v[c] = cbase[(size_t)c * HW];

    float objl = p[(size_t)a * HW + lclamp];
    const float* rb = p + (size_t)(3 + 3 * NCLS + a * 4) * HW + lclamp;
    float tx = rb[0], ty = rb[(size_t)HW], tw = rb[(size_t)2 * HW], th = rb[(size_t)3 * HW];

    // pass A: max (ascending, order-exact)
    float m = -INFINITY;
#pragma unroll
    for (int c = 0; c < NCLS; c++) m = fmaxf(m, v[c]);
    // pass B: serial ascending sum + argmax of e (strict >, ascending)
    float s = 0.f; float beste = -1.f; int bi = 0;
#pragma unroll
    for (int c = 0; c < NCLS; c++) {
        float e = expf(v[c] - m);
        s += e;
        if (e > beste) { beste = e; bi = c; }
    }
    float obj = sigmoidf_(objl);
    float best = beste / s * obj;             // == ref's (e/s)*obj at argmax

    if (!valid) return;

    const float AW[9] = {10.f,16.f,33.f, 30.f,62.f,59.f, 116.f,156.f,373.f};
    const float AH[9] = {13.f,30.f,23.f, 61.f,45.f,119.f, 90.f,198.f,326.f};
    float aw = AW[si*3 + a], ah = AH[si*3 + a];

    int y = local / W;
    int x = local - y * W;
    float cx = (sigmoidf_(tx) + (float)x) * stride;
    float cy = (sigmoidf_(ty) + (float)y) * stride;
    float bw = expf(tw) * aw;
    float bh = expf(th) * ah;
    float x1 = fminf(fmaxf((cx - bw / 2.f) / 640.f, 0.f), 1.f);
    float y1 = fminf(fmaxf((cy - bh / 2.f) / 640.f, 0.f), 1.f);
    float x2 = fminf(fmaxf((cx + bw / 2.f) / 640.f, 0.f), 1.f);
    float y2 = fminf(fmaxf((cy + bh / 2.f) / 640.f, 0.f), 1.f);

    int g = (base + local) * 3 + a;           // reference global ordering
    float clsf = (float)bi;
    float* o = out + (size_t)g * 7;
    o[0] = x1; o[1] = y1; o[2] = x2; o[3] = y2;
    o[4] = best; o[5] = clsf; o[6] = 0.f;

    if (best >= 0.001f) {
        float off2 = clsf * 2.0f;             // ref IoU uses class-offset boxes
        g_boxin[g] = make_float4(x1 + off2, y1 + off2, x2 + off2, y2 + off2);
        unsigned u = __float_as_uint(best);
        u = (u & 0x80000000u) ? ~u : (u | 0x80000000u);
        g_key[g] = ((uint64_t)bi << 47) | ((uint64_t)(~u) << 15) | (uint64_t)g;
    } else {
        g_key[g] = (uint64_t)127 << 47;       // sentinel class: never matched
    }
}

// wave-level bucket step: ballot-compact 2 keys/thread; lane0-atomic valid
// because active lanes are always a tid-prefix within the wave.
#define BUCKET2(kv)                                                       \
    {                                                                     \
        bool m0 = (int)((kv).x >> 47) == c;                               \
        bool m1 = (int)((kv).y >> 47) == c;                               \
        unsigned long long b0 = __ballot(m0);                             \
        unsigned long long b1 = __ballot(m1);                             \
        int total = __popcll(b0) + __popcll(b1);                          \
        int bs = 0;                                                       \
        if (lane == 0 && total) bs = atomicAdd(&ln_s, total);             \
        bs = __shfl(bs, 0);                                               \
        unsigned long long lower = ((unsigned long long)1 << lane) - 1;   \
        int off0 = bs + __popcll(b0 & lower);                             \
        int off1 = bs + __popcll(b0) + __popcll(b1 & lower);              \
        if (m0 && off0 < CAP) key_s[off0] = (kv).x;                       \
        if (m1 && off1 < CAP) key_s[off1] = (kv).y;                       \
    }

// ONE block per class, 1024 threads. BYTE-IDENTICAL to R9 (measured 34.5us
// via R10's 4x replication). This round replicates DECODE instead to
// separate decode's duration from the fixed window overhead.
__global__ __launch_bounds__(1024, 4) void nms_fused_kernel(
    const uint64_t* __restrict__ g_key, const float4* __restrict__ g_boxin,
    float* __restrict__ out)
{
    int c = blockIdx.x;
    int tid = threadIdx.x;

    __shared__ alignas(16) uint64_t key_s[CAP];   // 4 KB (class-c keys)
    __shared__ float4   boxu_s[CAP];              // 8 KB (matching offset boxes)
    __shared__ float4   sbox_s[CAP + 64];         // 9 KB (sorted, +64 sentinel)
    __shared__ int      sg_s[CAP];                // 2 KB (sorted -> pred idx)
    __shared__ uint64_t mask_s[MW * CAP];         // 32 KB (suppression bitmask)
    __shared__ int      ln_s;

    if (tid == 0) ln_s = 0;
    __syncthreads();

    // ---- phase 0: bucket class-c keys; 6 full strip-2 rounds + prefix tail
    {
        int lane = tid & 63;
        const ulonglong2* kp = (const ulonglong2*)g_key;
        const int HALF = NPRED / 2;          // 12600
        const int R2 = HALF >> 11;           // 6 full 2048-item rounds
        for (int r = 0; r < R2; r++) {
            int i0 = (r << 11) + tid;        // in-bounds for ALL threads
            ulonglong2 ka = kp[i0];
            ulonglong2 kb = kp[i0 + 1024];   // both loads in flight
            BUCKET2(ka);
            BUCKET2(kb);
        }
        int ti = (R2 << 11) + tid;           // 12288 + tid (prefix-active)
        if (ti < HALF) {
            ulonglong2 ka = kp[ti];
            BUCKET2(ka);
        }
    }
    __syncthreads();
    int n = ln_s; if (n > CAP) n = CAP;
    if (n == 0) return;                       // uniform (all read ln_s)
    int nw = (n + 63) >> 6;

    // ---- phase 0b: gather boxes by g; sentinel-fill pad for the IoU loop
    for (int i = tid; i < n; i += 1024)
        boxu_s[i] = g_boxin[key_s[i] & 0x7FFF];
    for (int i = n + tid; i < n + 64; i += 1024)
        sbox_s[i] = make_float4(3e30f, 3e30f, 3e30f, 3e30f);
    __syncthreads();

    // ---- rank-by-count sort (keys unique: low 15 bits = global pred idx).
    for (int i0 = 0; i0 < n; i0 += 256) {
        int item = i0 + (tid >> 2);
        int sub  = tid & 3;
        bool act = item < n;
        int r = 0;
        uint64_t k = 0;
        if (act) {
            k = key_s[item];
            int nq = (((n + 3) >> 2) + 1) & ~1;    // even, >= ceil(n/4)
            int lo = sub * nq; if (lo > n) lo = n; // lo even (or == n)
            int hi = lo + nq;  if (hi > n) hi = n;
            int jj = lo;
            for (; jj + 8 <= hi; jj += 8) {        // 4x ds_read_b128 in flight
                ulonglong2 p0 = *(const ulonglong2*)&key_s[jj];
                ulonglong2 p1 = *(const ulonglong2*)&key_s[jj + 2];
                ulonglong2 p2 = *(const ulonglong2*)&key_s[jj + 4];
                ulonglong2 p3 = *(const ulonglong2*)&key_s[jj + 6];
                r += (p0.x < k) + (p0.y < k) + (p1.x < k) + (p1.y < k)
                   + (p2.x < k) + (p2.y < k) + (p3.x < k) + (p3.y < k);
            }
            for (; jj + 2 <= hi; jj += 2) {
                ulonglong2 p0 = *(const ulonglong2*)&key_s[jj];
                r += (p0.x < k) + (p0.y < k);
            }
            if (jj < hi) r += (key_s[jj] < k);
        }
        r += __shfl_xor(r, 1);                // quad reduce (4 lanes/item)
        r += __shfl_xor(r, 2);
        if (act && sub == 0) {
            sbox_s[r] = boxu_s[item];
            sg_s[r]   = (int)(k & 0x7FFF);
        }
    }
    __syncthreads();

    // ---- mask build: upper-triangle words only, tiled as wave-tasks.
    {
        int wid   = tid >> 6;                 // 0..15
        int lane2 = tid & 63;
        int T = nw * (nw + 1) / 2;
        for (int t = wid; t < T; t += 16) {
            int w = 0, acc = 0;               // triangular decode (wave-uniform)
            while (t >= acc + w + 1) { acc += w + 1; w++; }
            int ib = t - acc;                 // 0..w
            int i  = (ib << 6) + lane2;       // <= n+62 (covered by pad)
            float4 b4 = sbox_s[i];
            float Ai = (b4.z - b4.x) * (b4.w - b4.y);
            int j0 = w << 6;
            float4 bjc = sbox_s[j0];
            uint64_t bits = 0;
#pragma unroll 8
            for (int jq = 0; jq < 64; jq++) {
                float4 bjn = sbox_s[j0 + ((jq + 1) & 63)];  // prefetch (wrap ok)
                float xx1 = fmaxf(b4.x, bjc.x);
                float yy1 = fmaxf(b4.y, bjc.y);
                float xx2 = fminf(b4.z, bjc.z);
                float yy2 = fminf(b4.w, bjc.w);
                float ww = fmaxf(1e-28f, xx2 - xx1);
                float hh = fmaxf(1e-28f, yy2 - yy1);
                float inter = ww * hh;
                float Aj = (bjc.z - bjc.x) * (bjc.w - bjc.y);
                float iou = inter / ((Ai + Aj) - inter);   // ref op order
                if ((j0 + jq) > i && iou > 0.6f) bits |= 1ull << jq;
                bjc = bjn;
            }
            if (i < n) mask_s[w * CAP + i] = bits;
        }
    }
    __syncthreads();

    // ---- greedy bitmask scan on wave 0 (== ref's fori_loop greedy NMS)
    if (tid >= 64) return;
    int lane = tid;
    uint64_t removed = 0;                      // lane L<8 holds word L
    for (int w = 0; w < nw; w++) {
        uint64_t rw = __shfl(removed, w);
        int row = (w << 6) + lane;
        uint64_t diag = (row < n) ? mask_s[w * CAP + row] : 0ull;
        int rem = n - (w << 6);
        uint64_t valid = (rem >= 64) ? ~0ull : ((1ull << rem) - 1ull);
        uint64_t nulls = __ballot(diag == 0ull);
        uint64_t cand = ~rw & valid;
        uint64_t kw = 0;
        uint64_t it = cand & ~nulls;           // rows with in-word forward bits
        while (it) {                           // uniform serial chain (rare rows)
            int b = __ffsll((unsigned long long)it) - 1;
            kw |= 1ull << b;
            uint64_t db = __shfl(diag, b);
            it &= ~db; cand &= ~db;
            it &= ~(1ull << b);
        }
        kw |= cand & nulls;                    // surviving zero-diag rows kept

        // cooperative fold: fixed predicated 8-read unroll.
        int g  = lane >> 3;
        int wp = lane & 7;
        uint64_t acc = 0;
        if (wp >= w && wp < nw) {
            int rbase = (w << 6) + (g << 3);
#pragma unroll
            for (int bb = 0; bb < 8; bb++) {
                uint64_t mword = mask_s[wp * CAP + rbase + bb];
                if ((kw >> ((g << 3) + bb)) & 1) acc |= mword;
            }
        }
        acc |= __shfl_xor(acc, 8);
        acc |= __shfl_xor(acc, 16);
        acc |= __shfl_xor(acc, 32);
        if (lane < MW) removed |= acc;

        if (row < n && ((kw >> lane) & 1))
            out[(size_t)sg_s[row] * 7 + 6] = 1.0f;
    }
}

extern "C" void kernel_launch(void* const* d_in, const int* in_sizes, int n_in,
                              void* d_out, int out_size, void* d_ws, size_t ws_size,
                              hipStream_t stream) {
    const float* ps = (const float*)d_in[0];
    const float* pm = (const float*)d_in[1];
    const float* pl = (const float*)d_in[2];
    float* out = (float*)d_out;

    char* ws = (char*)d_ws;
    float4*   g_boxin = (float4*)ws;                       // 403,200 B (dense by g)
    uint64_t* g_key   = (uint64_t*)(ws + 409600);          // 201,600 B (dense by g)

    // ATTRIBUTION: decode is idempotent; 4 launches => T = R9_total + 3x(decode+gap).
    // Separates decode's real duration from the fixed window overhead, which
    // every single-launch bench since R3 has conflated.
    decode_kernel<<<dim3(NCHUNK, 3), 64, 0, stream>>>(ps, pm, pl, out, g_boxin, g_key);
    decode_kernel<<<dim3(NCHUNK, 3), 64, 0, stream>>>(ps, pm, pl, out, g_boxin, g_key);
    decode_kernel<<<dim3(NCHUNK, 3), 64, 0, stream>>>(ps, pm, pl, out, g_boxin, g_key);
    decode_kernel<<<dim3(NCHUNK, 3), 64, 0, stream>>>(ps, pm, pl, out, g_boxin, g_key);
    nms_fused_kernel<<<NCLS, 1024, 0, stream>>>(g_key, g_boxin, out);
}

// Round 13
// 101.442 us; speedup vs baseline: 2.0807x; 1.1954x over previous
//
#include <hip/hip_runtime.h>
#include <cstdint>

#define NPRED 25200      // total predictions (8400 positions * 3 anchors)
#define NPOS  8400
#define NCLS  80
#define CAP   512        // max boxes per class (mean ~315, sigma ~18)
#define MW    8          // u64 mask words per row (512/64)
#define NCHUNK 132       // 64-position chunks: 100 (s0) + 25 (s1) + 7 (s2 tail)

__device__ __forceinline__ float sigmoidf_(float x) { return 1.0f / (1.0f + expf(-x)); }

// Block = (64-position chunk, anchor), 64 threads. REGISTER-RESIDENT class
// logits (v[80] in VGPRs; (64,2) bounds -> 256 VGPR cap, no spill).
// Measured ~4.5us (R12 4x-replication attribution). Op order exact.
__global__ __launch_bounds__(64, 2) void decode_kernel(
    const float* __restrict__ ps, const float* __restrict__ pm, const float* __restrict__ pl,
    float* __restrict__ out,
    float4* __restrict__ g_boxin, uint64_t* __restrict__ g_key)
{
    int chunk = blockIdx.x;
    int a     = blockIdx.y;
    int t     = threadIdx.x;

    const float* p; int HW, W, base, si; float stride; int w0;
    if (chunk < 100)      { p = ps; HW = 6400; W = 80; stride = 8.f;  base = 0;    si = 0; w0 = chunk * 64; }
    else if (chunk < 125) { p = pm; HW = 1600; W = 40; stride = 16.f; base = 6400; si = 1; w0 = (chunk - 100) * 64; }
    else                  { p = pl; HW = 400;  W = 20; stride = 32.f; base = 8000; si = 2; w0 = (chunk - 125) * 64; }

    int local = w0 + t;
    bool valid = local < HW;
    int lclamp = valid ? local : (HW - 1);

    const float* cbase = p + (size_t)(3 + a * NCLS) * HW + lclamp;
    float v[NCLS];
#pragma unroll
    for (int c = 0; c < NCLS; c++) v[c] = cbase[(size_t)c * HW];

    float objl = p[(size_t)a * HW + lclamp];
    const float* rb = p + (size_t)(3 + 3 * NCLS + a * 4) * HW + lclamp;
    float tx = rb[0], ty = rb[(size_t)HW], tw = rb[(size_t)2 * HW], th = rb[(size_t)3 * HW];

    // pass A: max (ascending, order-exact)
    float m = -INFINITY;
#pragma unroll
    for (int c = 0; c < NCLS; c++) m = fmaxf(m, v[c]);
    // pass B: serial ascending sum + argmax of e (strict >, ascending)
    float s = 0.f; float beste = -1.f; int bi = 0;
#pragma unroll
    for (int c = 0; c < NCLS; c++) {
        float e = expf(v[c] - m);
        s += e;
        if (e > beste) { beste = e; bi = c; }
    }
    float obj = sigmoidf_(objl);
    float best = beste / s * obj;             // == ref's (e/s)*obj at argmax

    if (!valid) return;

    const float AW[9] = {10.f,16.f,33.f, 30.f,62.f,59.f, 116.f,156.f,373.f};
    const float AH[9] = {13.f,30.f,23.f, 61.f,45.f,119.f, 90.f,198.f,326.f};
    float aw = AW[si*3 + a], ah = AH[si*3 + a];

    int y = local / W;
    int x = local - y * W;
    float cx = (sigmoidf_(tx) + (float)x) * stride;
    float cy = (sigmoidf_(ty) + (float)y) * stride;
    float bw = expf(tw) * aw;
    float bh = expf(th) * ah;
    float x1 = fminf(fmaxf((cx - bw / 2.f) / 640.f, 0.f), 1.f);
    float y1 = fminf(fmaxf((cy - bh / 2.f) / 640.f, 0.f), 1.f);
    float x2 = fminf(fmaxf((cx + bw / 2.f) / 640.f, 0.f), 1.f);
    float y2 = fminf(fmaxf((cy + bh / 2.f) / 640.f, 0.f), 1.f);

    int g = (base + local) * 3 + a;           // reference global ordering
    float clsf = (float)bi;
    float* o = out + (size_t)g * 7;
    o[0] = x1; o[1] = y1; o[2] = x2; o[3] = y2;
    o[4] = best; o[5] = clsf; o[6] = 0.f;

    if (best >= 0.001f) {
        float off2 = clsf * 2.0f;             // ref IoU uses class-offset boxes
        g_boxin[g] = make_float4(x1 + off2, y1 + off2, x2 + off2, y2 + off2);
        unsigned u = __float_as_uint(best);
        u = (u & 0x80000000u) ? ~u : (u | 0x80000000u);
        g_key[g] = ((uint64_t)bi << 47) | ((uint64_t)(~u) << 15) | (uint64_t)g;
    } else {
        g_key[g] = (uint64_t)127 << 47;       // sentinel class: never matched
    }
}

// exact ref IoU expression/order; sets bit JQ of `bits`
#define IOUBIT(BJ, JQ)                                                   \
    {                                                                    \
        float xx1 = fmaxf(b4.x, (BJ).x);                                 \
        float yy1 = fmaxf(b4.y, (BJ).y);                                 \
        float xx2 = fminf(b4.z, (BJ).z);                                 \
        float yy2 = fminf(b4.w, (BJ).w);                                 \
        float ww = fmaxf(1e-28f, xx2 - xx1);                             \
        float hh = fmaxf(1e-28f, yy2 - yy1);                             \
        float inter = ww * hh;                                           \
        float Aj = ((BJ).z - (BJ).x) * ((BJ).w - (BJ).y);                \
        float iou = inter / ((Ai + Aj) - inter);                         \
        if ((j0 + (JQ)) > i && iou > 0.6f) bits |= 1ull << (JQ);         \
    }

// ONE block per class, 1024 threads. R12 attribution: fused = 34.5us vs a
// ~7us work model -- all latency exposure. This version kills the two
// longest dependency chains:
//  * p0: two-pass prefix-sum bucketing (13 independent loads/thread, NO
//    per-iter ballot/atomic/shfl chain; shfl-prefix + 16-wave LDS prefix).
//    Bucket order changes -- irrelevant (unique keys, rank-by-count total).
//  * build: 8 explicit independent broadcast loads per chunk (R9's rotation
//    was a 1-deep serial chain: 64x ~120cyc per tile, ~10us total).
// Sort/scan unchanged from R9. Float op order bit-identical throughout.
__global__ __launch_bounds__(1024, 4) void nms_fused_kernel(
    const uint64_t* __restrict__ g_key, const float4* __restrict__ g_boxin,
    float* __restrict__ out)
{
    int c = blockIdx.x;
    int tid = threadIdx.x;
    int wid  = tid >> 6;
    int lane = tid & 63;

    __shared__ alignas(16) uint64_t key_s[CAP];   // 4 KB (class-c keys)
    __shared__ float4   boxu_s[CAP];              // 8 KB (matching offset boxes)
    __shared__ float4   sbox_s[CAP + 64];         // 9 KB (sorted, +64 sentinel)
    __shared__ int      sg_s[CAP];                // 2 KB (sorted -> pred idx)
    __shared__ uint64_t mask_s[MW * CAP];         // 32 KB (suppression bitmask)
    __shared__ int      wsum[16];                 // per-wave match totals

    // ---- phase 0 pass 1: count matches (13 independent ulonglong2 loads,
    // fully pipelined -- no cross-lane ops in the loop)
    const ulonglong2* kp = (const ulonglong2*)g_key;
    const int HALF = NPRED / 2;              // 12600
    int cnt = 0;
#pragma unroll
    for (int j = 0; j < 13; j++) {
        int idx = j * 1024 + tid;
        if (idx < HALF) {
            ulonglong2 kv = kp[idx];
            cnt += ((int)(kv.x >> 47) == c) + ((int)(kv.y >> 47) == c);
        }
    }
    // wave-inclusive shfl prefix (6 steps)
    int pre = cnt;
#pragma unroll
    for (int d = 1; d < 64; d <<= 1) {
        int vv = __shfl_up(pre, d);
        if (lane >= d) pre += vv;
    }
    if (lane == 63) wsum[wid] = pre;         // wave total
    __syncthreads();
    int wbase = 0, ntot = 0;
#pragma unroll
    for (int wq = 0; wq < 16; wq++) {        // 16 LDS reads (broadcast)
        int t16 = wsum[wq];
        if (wq < wid) wbase += t16;
        ntot += t16;
    }
    int base = wbase + pre - cnt;            // exclusive prefix for this thread

    // ---- phase 0 pass 2: re-read (L1-hot) and write at computed offsets
    {
        int wr = base;
#pragma unroll
        for (int j = 0; j < 13; j++) {
            int idx = j * 1024 + tid;
            if (idx < HALF) {
                ulonglong2 kv = kp[idx];
                if ((int)(kv.x >> 47) == c && wr < CAP) key_s[wr++] = kv.x;
                if ((int)(kv.y >> 47) == c && wr < CAP) key_s[wr++] = kv.y;
            }
        }
    }
    __syncthreads();
    int n = ntot; if (n > CAP) n = CAP;
    if (n == 0) return;                       // uniform
    int nw = (n + 63) >> 6;

    // ---- phase 0b: gather boxes by g; sentinel-fill pad for the IoU loop
    for (int i = tid; i < n; i += 1024)
        boxu_s[i] = g_boxin[key_s[i] & 0x7FFF];
    for (int i = n + tid; i < n + 64; i += 1024)
        sbox_s[i] = make_float4(3e30f, 3e30f, 3e30f, 3e30f);
    __syncthreads();

    // ---- rank-by-count sort (keys unique: low 15 bits = global pred idx).
    for (int i0 = 0; i0 < n; i0 += 256) {
        int item = i0 + (tid >> 2);
        int sub  = tid & 3;
        bool act = item < n;
        int r = 0;
        uint64_t k = 0;
        if (act) {
            k = key_s[item];
            int nq = (((n + 3) >> 2) + 1) & ~1;    // even, >= ceil(n/4)
            int lo = sub * nq; if (lo > n) lo = n; // lo even (or == n)
            int hi = lo + nq;  if (hi > n) hi = n;
            int jj = lo;
            for (; jj + 8 <= hi; jj += 8) {        // 4x ds_read_b128 in flight
                ulonglong2 p0 = *(const ulonglong2*)&key_s[jj];
                ulonglong2 p1 = *(const ulonglong2*)&key_s[jj + 2];
                ulonglong2 p2 = *(const ulonglong2*)&key_s[jj + 4];
                ulonglong2 p3 = *(const ulonglong2*)&key_s[jj + 6];
                r += (p0.x < k) + (p0.y < k) + (p1.x < k) + (p1.y < k)
                   + (p2.x < k) + (p2.y < k) + (p3.x < k) + (p3.y < k);
            }
            for (; jj + 2 <= hi; jj += 2) {
                ulonglong2 p0 = *(const ulonglong2*)&key_s[jj];
                r += (p0.x < k) + (p0.y < k);
            }
            if (jj < hi) r += (key_s[jj] < k);
        }
        r += __shfl_xor(r, 1);                // quad reduce (4 lanes/item)
        r += __shfl_xor(r, 2);
        if (act && sub == 0) {
            sbox_s[r] = boxu_s[item];
            sg_s[r]   = (int)(k & 0x7FFF);
        }
    }
    __syncthreads();

    // ---- mask build: upper-triangle words, wave-task tiles; 8 independent
    // broadcast loads in flight per chunk (direct indexing, no rotation).
    {
        int T = nw * (nw + 1) / 2;
        for (int t = wid; t < T; t += 16) {
            int w = 0, acc = 0;               // triangular decode (wave-uniform)
            while (t >= acc + w + 1) { acc += w + 1; w++; }
            int ib = t - acc;                 // 0..w
            int i  = (ib << 6) + lane;        // <= n+62 (covered by pad)
            float4 b4 = sbox_s[i];
            float Ai = (b4.z - b4.x) * (b4.w - b4.y);
            int j0 = w << 6;
            uint64_t bits = 0;
#pragma unroll
            for (int jq0 = 0; jq0 < 64; jq0 += 8) {
                float4 q0 = sbox_s[j0 + jq0 + 0];   // 8 broadcast b128 reads
                float4 q1 = sbox_s[j0 + jq0 + 1];   // issued independently
                float4 q2 = sbox_s[j0 + jq0 + 2];
                float4 q3 = sbox_s[j0 + jq0 + 3];
                float4 q4 = sbox_s[j0 + jq0 + 4];
                float4 q5 = sbox_s[j0 + jq0 + 5];
                float4 q6 = sbox_s[j0 + jq0 + 6];
                float4 q7 = sbox_s[j0 + jq0 + 7];
                IOUBIT(q0, jq0 + 0); IOUBIT(q1, jq0 + 1);
                IOUBIT(q2, jq0 + 2); IOUBIT(q3, jq0 + 3);
                IOUBIT(q4, jq0 + 4); IOUBIT(q5, jq0 + 5);
                IOUBIT(q6, jq0 + 6); IOUBIT(q7, jq0 + 7);
            }
            if (i < n) mask_s[w * CAP + i] = bits;
        }
    }
    __syncthreads();

    // ---- greedy bitmask scan on wave 0 (== ref's fori_loop greedy NMS)
    if (tid >= 64) return;
    uint64_t removed = 0;                      // lane L<8 holds word L
    for (int w = 0; w < nw; w++) {
        uint64_t rw = __shfl(removed, w);
        int row = (w << 6) + lane;
        uint64_t diag = (row < n) ? mask_s[w * CAP + row] : 0ull;
        int rem = n - (w << 6);
        uint64_t valid = (rem >= 64) ? ~0ull : ((1ull << rem) - 1ull);
        uint64_t nulls = __ballot(diag == 0ull);
        uint64_t cand = ~rw & valid;
        uint64_t kw = 0;
        uint64_t it = cand & ~nulls;           // rows with in-word forward bits
        while (it) {                           // uniform serial chain (rare rows)
            int b = __ffsll((unsigned long long)it) - 1;
            kw |= 1ull << b;
            uint64_t db = __shfl(diag, b);
            it &= ~db; cand &= ~db;
            it &= ~(1ull << b);
        }
        kw |= cand & nulls;                    // surviving zero-diag rows kept

        // cooperative fold: fixed predicated 8-read unroll.
        int g  = lane >> 3;
        int wp = lane & 7;
        uint64_t acc = 0;
        if (wp >= w && wp < nw) {
            int rbase = (w << 6) + (g << 3);
#pragma unroll
            for (int bb = 0; bb < 8; bb++) {
                uint64_t mword = mask_s[wp * CAP + rbase + bb];
                if ((kw >> ((g << 3) + bb)) & 1) acc |= mword;
            }
        }
        acc |= __shfl_xor(acc, 8);
        acc |= __shfl_xor(acc, 16);
        acc |= __shfl_xor(acc, 32);
        if (lane < MW) removed |= acc;

        if (row < n && ((kw >> lane) & 1))
            out[(size_t)sg_s[row] * 7 + 6] = 1.0f;
    }
}

extern "C" void kernel_launch(void* const* d_in, const int* in_sizes, int n_in,
                              void* d_out, int out_size, void* d_ws, size_t ws_size,
                              hipStream_t stream) {
    const float* ps = (const float*)d_in[0];
    const float* pm = (const float*)d_in[1];
    const float* pl = (const float*)d_in[2];
    float* out = (float*)d_out;

    char* ws = (char*)d_ws;
    float4*   g_boxin = (float4*)ws;                       // 403,200 B (dense by g)
    uint64_t* g_key   = (uint64_t*)(ws + 409600);          // 201,600 B (dense by g)

    decode_kernel<<<dim3(NCHUNK, 3), 64, 0, stream>>>(ps, pm, pl, out, g_boxin, g_key);
    nms_fused_kernel<<<NCLS, 1024, 0, stream>>>(g_key, g_boxin, out);
}